// Round 10
// baseline (566.384 us; speedup 1.0000x reference)
//
#include <hip/hip_runtime.h>
#include <hip/hip_bf16.h>

// ---------- types ----------
typedef __attribute__((ext_vector_type(8))) short short8;
typedef __attribute__((ext_vector_type(4))) float f32x4;

#define MROWS 4096      // b*l
#define CDIM  1024
#define HEADS 16
#define DHEAD 64
#define NSEQ  1024

// ---------- small device helpers ----------
__device__ inline float softw(const float* __restrict__ w, int idx) {
    // softmax(w/0.01)[idx] over 6 entries
    float m = w[0];
#pragma unroll
    for (int i = 1; i < 6; i++) m = fmaxf(m, w[i]);
    float s = 0.f, v = 0.f;
#pragma unroll
    for (int i = 0; i < 6; i++) {
        float e = __expf((w[i] - m) * 100.0f);
        s += e;
        if (i == idx) v = e;
    }
    return v / s;
}

__device__ inline float gelu_f(float x) {
    return 0.5f * x * (1.0f + erff(x * 0.70710678118654752f));
}

// ---------- prologue: x -> bf16 (vectorized), zero attn-map accumulator ----------
__global__ __launch_bounds__(256) void mix_base(
    const float* __restrict__ x_list, __hip_bfloat16* __restrict__ xb,
    float* __restrict__ am_acc)
{
    int i2 = blockIdx.x * 256 + threadIdx.x;   // 0 .. 2M-1, 2 elems/thread
    float4 v = ((const float4*)x_list)[i2];    // (x0,x1) pairs for elems 2*i2, 2*i2+1
    __hip_bfloat162 o;
    o.x = __float2bfloat16(v.y);
    o.y = __float2bfloat16(v.w);
    ((__hip_bfloat162*)xb)[i2] = o;
    if (i2 < 4096) am_acc[i2] = 0.f;
}

// ---------- fused fp32 -> bf16 weight convert (all weights, 1 launch) ----------
// wcat row-major [5248][1024]: rows 0..1023 conv_w, 1024..5119 mlp1_w,
// 5120..5183 ca1_w (fused-ca1 columns), 5184..5247 zero padding.
__global__ __launch_bounds__(256) void f2b_all(
    const float* __restrict__ conv_w, const float* __restrict__ mlp1_w,
    const float* __restrict__ qkv_w, const float* __restrict__ proj_w,
    const float* __restrict__ mlp2_w, const float* __restrict__ ca1_w,
    __hip_bfloat16* __restrict__ wcat, __hip_bfloat16* __restrict__ qkvwb,
    __hip_bfloat16* __restrict__ projwb, __hip_bfloat16* __restrict__ mlp2wb)
{
    size_t e = ((size_t)blockIdx.x * 256 + threadIdx.x) * 4;
    const float* src; __hip_bfloat16* dst; size_t o;
    if (e < 1048576)       { src = conv_w; dst = wcat;           o = e; }
    else if (e < 5242880)  { src = mlp1_w; dst = wcat + 1048576; o = e - 1048576; }
    else if (e < 5308416)  { src = ca1_w;  dst = wcat + 5242880; o = e - 5242880; }
    else if (e < 5373952) {
        // zero pad rows 5184..5247 (read into LDS, MFMA'd, never stored)
        __hip_bfloat162 z; z.x = __float2bfloat16(0.f); z.y = z.x;
        __hip_bfloat16* d = wcat + 5308416 + (e - 5308416);
        *(__hip_bfloat162*)(d)     = z;
        *(__hip_bfloat162*)(d + 2) = z;
        return;
    }
    else if (e < 8519680)  { src = qkv_w;  dst = qkvwb;          o = e - 5373952; }
    else if (e < 9568256)  { src = proj_w; dst = projwb;         o = e - 8519680; }
    else                   { src = mlp2_w; dst = mlp2wb;         o = e - 9568256; }
    float4 v = *(const float4*)(src + o);
    __hip_bfloat162 a, b;
    a.x = __float2bfloat16(v.x); a.y = __float2bfloat16(v.y);
    b.x = __float2bfloat16(v.z); b.y = __float2bfloat16(v.w);
    *(__hip_bfloat162*)(dst + o)     = a;
    *(__hip_bfloat162*)(dst + o + 2) = b;
}

// ---------- bf16 MFMA GEMM, dbuf LDS + depth-2 register prefetch ----------
// Verified-fast 2-phase core. EPI=1 is the in-run environment control.
// SWZ=0: natural 2D. SWZ=1: XCD row-chunk remap (mlp2/qkv/proj).
// SWZ=2: EPI=1 only -- 1D grid of 1312; blocks 0..1279 use the exact 40-wide
//   x-fastest map (XCD = bx%8 pinning: B/x_list panels stay in one L2 each;
//   round-8's 41-wide grid broke this -> FETCH 61->182 MB), ca1/pad column
//   (bx=40) appended as blocks 1280..1311 (runs last, no added tail).
// EPI: 1=fused conv+mlp1+ca1, 3=mlp2 rmw, 4=proj+residual,
//      5=qkv+per-head LN (q gain x 0.125*log2e: folds 1/sqrt(d) AND the
//        exp->exp2 conversion for flash/attn_map; exact softmax invariance).
#define BKT 32
#define LDA 40   // 32 + 8 pad (16B aligned rows: 80 B; 2-way LDS banks = free)

template<int EPI, int FM, int FN, int SWZ>
__global__ __launch_bounds__(256) void gemm_bf16(
    const __hip_bfloat16* __restrict__ A, const __hip_bfloat16* __restrict__ W,
    const float* __restrict__ bias,
    float* __restrict__ f0, const float* __restrict__ f1,
    __hip_bfloat16* __restrict__ b0, __hip_bfloat16* __restrict__ b1,
    __hip_bfloat16* __restrict__ b2,
    const float* __restrict__ g0, const float* __restrict__ be0,
    const float* __restrict__ g1, const float* __restrict__ be1,
    const float* __restrict__ wvec, int M, int N, int K)
{
    constexpr int BMt = FM * 32;
    constexpr int BNt = FN * 32;
    constexpr int NA = BMt / 64;    // short8 staged per thread (A)
    constexpr int NB = BNt / 64;    // short8 staged per thread (B)
    __shared__ __hip_bfloat16 As[2][BMt * LDA];
    __shared__ __hip_bfloat16 Bs[2][BNt * LDA];
    int t = threadIdx.x;
    int bx = blockIdx.x, by = blockIdx.y;
    if constexpr (SWZ == 1) {
        // bijective XCD remap; requires nwg % 8 == 0
        int nx = gridDim.x;
        int lin = by * nx + bx;
        int cpx = (nx * gridDim.y) >> 3;
        int swz = (lin & 7) * cpx + (lin >> 3);
        bx = swz % nx;
        by = swz / nx;
    }
    if constexpr (SWZ == 2) {
        int l = blockIdx.x;          // 1D grid of 1312
        if (l < 1280) { bx = l % 40; by = l / 40; }  // original pinned map
        else          { bx = 40;     by = l - 1280; } // ca1+pad column, last
    }
    int n0 = bx * BNt, m0 = by * BMt;
    int wave = t >> 6, lane = t & 63;
    int wr = wave >> 1, wc = wave & 1;
    int quad = lane >> 4, l16 = lane & 15;
    int r0 = t >> 2, c0 = (t & 3) * 8;    // staging: 4 lanes/row, 64 rows/round

    short8 sa0[NA], sb0[NB], sa1[NA], sb1[NB];
    auto ldg = [&](int k0, short8* da, short8* db) {
#pragma unroll
        for (int i = 0; i < NA; i++)
            da[i] = *(const short8*)(A + (size_t)(m0 + r0 + 64 * i) * K + k0 + c0);
#pragma unroll
        for (int i = 0; i < NB; i++)
            db[i] = *(const short8*)(W + (size_t)(n0 + r0 + 64 * i) * K + k0 + c0);
    };
    ldg(0, sa0, sb0);
    ldg(BKT, sa1, sb1);

    f32x4 zero = {0.f, 0.f, 0.f, 0.f};
    f32x4 acc[FM][FN];
#pragma unroll
    for (int i = 0; i < FM; i++)
#pragma unroll
        for (int j = 0; j < FN; j++) acc[i][j] = zero;

    for (int k0 = 0; k0 < K; k0 += 2 * BKT) {
        // ---- even half: buffer 0 ----
#pragma unroll
        for (int i = 0; i < NA; i++)
            *(short8*)&As[0][(r0 + 64 * i) * LDA + c0] = sa0[i];
#pragma unroll
        for (int i = 0; i < NB; i++)
            *(short8*)&Bs[0][(r0 + 64 * i) * LDA + c0] = sb0[i];
        __syncthreads();
        if (k0 + 2 * BKT < K) ldg(k0 + 2 * BKT, sa0, sb0);
        {
            short8 af[FM], bf[FN];
#pragma unroll
            for (int i = 0; i < FM; i++)
                af[i] = *(const short8*)&As[0][(wr * FM * 16 + i * 16 + l16) * LDA + quad * 8];
#pragma unroll
            for (int j = 0; j < FN; j++)
                bf[j] = *(const short8*)&Bs[0][(wc * FN * 16 + j * 16 + l16) * LDA + quad * 8];
#pragma unroll
            for (int i = 0; i < FM; i++)
#pragma unroll
                for (int j = 0; j < FN; j++)
                    acc[i][j] = __builtin_amdgcn_mfma_f32_16x16x32_bf16(
                        af[i], bf[j], acc[i][j], 0, 0, 0);
        }
        // ---- odd half: buffer 1 ----
#pragma unroll
        for (int i = 0; i < NA; i++)
            *(short8*)&As[1][(r0 + 64 * i) * LDA + c0] = sa1[i];
#pragma unroll
        for (int i = 0; i < NB; i++)
            *(short8*)&Bs[1][(r0 + 64 * i) * LDA + c0] = sb1[i];
        __syncthreads();
        if (k0 + 3 * BKT < K) ldg(k0 + 3 * BKT, sa1, sb1);
        {
            short8 af[FM], bf[FN];
#pragma unroll
            for (int i = 0; i < FM; i++)
                af[i] = *(const short8*)&As[1][(wr * FM * 16 + i * 16 + l16) * LDA + quad * 8];
#pragma unroll
            for (int j = 0; j < FN; j++)
                bf[j] = *(const short8*)&Bs[1][(wc * FN * 16 + j * 16 + l16) * LDA + quad * 8];
#pragma unroll
            for (int i = 0; i < FM; i++)
#pragma unroll
                for (int j = 0; j < FN; j++)
                    acc[i][j] = __builtin_amdgcn_mfma_f32_16x16x32_bf16(
                        af[i], bf[j], acc[i][j], 0, 0, 0);
        }
    }

    if constexpr (EPI == 1) {
        // fused conv (cols 0..1023) + mlp1 (1024..5119) + ca1 (5120..5183) +
        // pad (5184..5247, skip). All boundaries 64-aligned -> wave-uniform.
        float wmx = softw(wvec, 2);
        float w0c = softw(wvec, 0);
        float w14c = softw(wvec, 1) + softw(wvec, 4);
        int colbase = n0 + wc * FN * 16;
        int region = (colbase < 1024) ? 0 : (colbase < 5120) ? 1
                   : (colbase < 5184) ? 2 : 3;
        if (region == 3) return;   // padding columns
#pragma unroll
        for (int i = 0; i < FM; i++) {
#pragma unroll
            for (int j = 0; j < FN; j++) {
                int col = colbase + j * 16 + l16;
                float bv = (region == 0) ? bias[col]
                         : (region == 1) ? be0[col - 1024]
                                         : g0[col - 5120];   // ca1_b
#pragma unroll
                for (int r = 0; r < 4; r++) {
                    int row = m0 + wr * FM * 16 + i * 16 + quad * 4 + r;
                    float v = acc[i][j][r] + bv;
                    if (region == 0) {
                        size_t idx = (size_t)row * 1024 + col;
                        float2 xl = ((const float2*)f1)[idx];
                        b0[idx] = __float2bfloat16(
                            w0c * xl.x + w14c * xl.y + wmx * gelu_f(v));
                    } else if (region == 1) {
                        b1[(size_t)row * 4096 + (col - 1024)] =
                            __float2bfloat16(gelu_f(v));
                    } else {
                        // ca1: h1 = relu(x @ ca1_w^T + b), f32
                        f0[(size_t)row * 64 + (col - 5120)] = fmaxf(v, 0.f);
                    }
                }
            }
        }
        return;
    }

    if constexpr (EPI == 5) {
        int colbase = n0 + wc * FN * 16;           // 64-aligned => one head per wave
        int portion = colbase >> 10;               // 0=q 1=k 2=v
        int hh = (colbase >> 6) & 15;
        float bv[FN];
#pragma unroll
        for (int j = 0; j < FN; j++) bv[j] = bias[colbase + j * 16 + l16];
        if (portion == 2) {
#pragma unroll
            for (int i = 0; i < FM; i++)
#pragma unroll
                for (int j = 0; j < FN; j++)
#pragma unroll
                    for (int r = 0; r < 4; r++) {
                        int row = m0 + wr * FM * 16 + i * 16 + quad * 4 + r;
                        int bb = row >> 10, nn = row & 1023;
                        int dd = j * 16 + l16;
                        b0[((size_t)(bb * 16 + hh) * DHEAD + dd) * NSEQ + nn] =
                            __float2bfloat16(acc[i][j][r] + bv[j]);
                    }
        } else {
            const float* g  = (portion == 0) ? g0 : g1;
            const float* be = (portion == 0) ? be0 : be1;
            __hip_bfloat16* dst = (portion == 0) ? b1 : b2;
            // q gain: 1/sqrt(d)=0.125 AND log2(e) (flash/attn_map use exp2)
            float qs = (portion == 0) ? 0.125f * 1.4426950408889634f : 1.0f;
            float gv[FN], bev[FN];
#pragma unroll
            for (int j = 0; j < FN; j++) {
                gv[j] = g[j * 16 + l16] * qs;
                bev[j] = be[j * 16 + l16] * qs;
            }
#pragma unroll
            for (int i = 0; i < FM; i++)
#pragma unroll
                for (int r = 0; r < 4; r++) {
                    float s1 = 0.f, s2 = 0.f;
#pragma unroll
                    for (int j = 0; j < FN; j++) {
                        float v = acc[i][j][r] + bv[j];
                        s1 += v; s2 += v * v;
                    }
#pragma unroll
                    for (int mk = 1; mk < 16; mk <<= 1) {
                        s1 += __shfl_xor(s1, mk, 64);
                        s2 += __shfl_xor(s2, mk, 64);
                    }
                    float mean = s1 * (1.f / 64.f);
                    float var = s2 * (1.f / 64.f) - mean * mean;
                    float rs = rsqrtf(var + 1e-5f);
                    int row = m0 + wr * FM * 16 + i * 16 + quad * 4 + r;
                    int bb = row >> 10, nn = row & 1023;
                    size_t base = ((size_t)(bb * 16 + hh) * NSEQ + nn) * DHEAD;
#pragma unroll
                    for (int j = 0; j < FN; j++)
                        dst[base + j * 16 + l16] = __float2bfloat16(
                            (acc[i][j][r] + bv[j] - mean) * rs * gv[j] + bev[j]);
                }
        }
        return;
    }

    float wmx = 0.f;
    if (EPI == 3) wmx = softw(wvec, 5);

#pragma unroll
    for (int i = 0; i < FM; i++) {
#pragma unroll
        for (int j = 0; j < FN; j++) {
            int col = n0 + wc * FN * 16 + j * 16 + l16;
            float bv = bias[col];
#pragma unroll
            for (int r = 0; r < 4; r++) {
                int row = m0 + wr * FM * 16 + i * 16 + quad * 4 + r;
                float v = acc[i][j][r] + bv;
                size_t idx = (size_t)row * N + col;
                if (EPI == 3) {
                    // final mix: xmixb += w5 * v (bf16 rmw)
                    float tv = __bfloat162float(b0[idx]) + wmx * v;
                    b0[idx] = __float2bfloat16(tv);
                } else if (EPI == 4) {
                    f0[idx] = v + __bfloat162float(b1[idx]);  // proj + residual
                }
            }
        }
    }
}

// ---------- ca2: xmixb += w3 * sigmoid(h1 @ ca2_w^T + b) * x  (bf16 rmw) ----------
__global__ __launch_bounds__(256) void ca2_kernel(
    const float* __restrict__ h1, const float* __restrict__ w,
    const float* __restrict__ bias, const __hip_bfloat16* __restrict__ xb,
    __hip_bfloat16* __restrict__ xmixb, const float* __restrict__ wvec)
{
    __shared__ float Wt[256 * 65];
    __shared__ float hs[16 * 64];
    int t = threadIdx.x;
    int m0 = blockIdx.x * 16, n0 = blockIdx.y * 256;
#pragma unroll
    for (int i = 0; i < 64; i++) {
        int e = t + i * 256; int r = e >> 6, c = e & 63;
        Wt[r * 65 + c] = w[(size_t)(n0 + r) * 64 + c];
    }
#pragma unroll
    for (int i = 0; i < 4; i++) {
        int e = t + i * 256; int r = e >> 6, c = e & 63;
        hs[r * 64 + c] = h1[(size_t)(m0 + r) * 64 + c];
    }
    __syncthreads();
    int n = n0 + t;
    float bv = bias[n];
    float acc[16];
#pragma unroll
    for (int mi = 0; mi < 16; mi++) acc[mi] = bv;
    for (int k = 0; k < 64; k++) {
        float wv = Wt[t * 65 + k];
#pragma unroll
        for (int mi = 0; mi < 16; mi++) acc[mi] += hs[mi * 64 + k] * wv;
    }
    float w3 = softw(wvec, 3);
#pragma unroll
    for (int mi = 0; mi < 16; mi++) {
        size_t idx = (size_t)(m0 + mi) * 1024 + n;
        float sg = 1.f / (1.f + __expf(-acc[mi]));
        float cur = __bfloat162float(xmixb[idx]);
        xmixb[idx] = __float2bfloat16(cur + w3 * sg * __bfloat162float(xb[idx]));
    }
}

// ---------- MFMA flash attention ----------
// grid (64 bh, 8 i-tiles), block 256 (4 waves). Wave owns 32 q-rows.
// XCD swizzle (T1): XCD k serves heads 8k..8k+7 -> K/V L2-resident per XCD.
// BOUNDED softmax (q,k LayerNormed => |s| <= 8*log2e): p = 2^s directly,
// no running max (exact; q carries 0.125*log2e from qkv epilogue).
// ROW-SUM VIA MFMA: synthetic ones-fragment (l16==0 lanes = bf16(1.0)) as a
// 5th PV B-tile -> o[ri][4] accumulates sum_j p in the l16==0 lanes; replaces
// the per-j-tile shfl_xor reduction (~100 VALU cyc) with 4 MFMA + 8 final shfl.
#define PSTR 72   // bf16 stride: 144 B, 16B-aligned, 2-way banks
__global__ __launch_bounds__(256) void flash_mfma(
    const __hip_bfloat16* __restrict__ qb, const __hip_bfloat16* __restrict__ kb,
    const __hip_bfloat16* __restrict__ vt, __hip_bfloat16* __restrict__ ao)
{
    __shared__ __hip_bfloat16 Plds[4][32 * PSTR];
    int l = blockIdx.y * 64 + blockIdx.x;      // hw linear id (x fastest)
    int swz = (l & 7) * 64 + (l >> 3);         // bijection on [0,512)
    int bh = swz >> 3;
    int i0 = (swz & 7) * 128;
    int b = bh >> 4, h = bh & 15;
    int t = threadIdx.x, wave = t >> 6, lane = t & 63;
    int l16 = lane & 15, quad = lane >> 4;
    const __hip_bfloat16* qbase = qb + (size_t)bh * NSEQ * DHEAD;
    const __hip_bfloat16* kbase = kb + (size_t)bh * NSEQ * DHEAD;
    const __hip_bfloat16* vbase = vt + (size_t)bh * DHEAD * NSEQ;
    __hip_bfloat16* pw = Plds[wave];
    int qrow0 = i0 + wave * 32;

    // Q fragments, held for the whole kernel (pre-scaled in qkv epi)
    short8 aq[2][2];
#pragma unroll
    for (int ri = 0; ri < 2; ri++)
#pragma unroll
        for (int ks = 0; ks < 2; ks++)
            aq[ri][ks] = *(const short8*)(qbase +
                (size_t)(qrow0 + ri * 16 + l16) * DHEAD + ks * 32 + quad * 8);

    // ones-fragment: B row 64 == 1.0 (lanes l16==0), rows 65..79 == 0
    short8 bones;
    {
        short fill = (l16 == 0) ? (short)0x3F80 : (short)0;
#pragma unroll
        for (int z = 0; z < 8; z++) bones[z] = fill;
    }

    f32x4 zero = {0.f, 0.f, 0.f, 0.f};
    f32x4 o[2][5];                 // [..][4] = row-sum accumulator
#pragma unroll
    for (int ri = 0; ri < 2; ri++)
#pragma unroll
        for (int nt = 0; nt < 5; nt++) o[ri][nt] = zero;

    for (int j0 = 0; j0 < NSEQ; j0 += 64) {
        // K fragments: B[n=key][k=d]
        short8 bk[4][2];
#pragma unroll
        for (int jt = 0; jt < 4; jt++)
#pragma unroll
            for (int ks = 0; ks < 2; ks++)
                bk[jt][ks] = *(const short8*)(kbase +
                    (size_t)(j0 + jt * 16 + l16) * DHEAD + ks * 32 + quad * 8);
        // V^T fragments: B[n=d][k=key]
        short8 bv[4][2];
#pragma unroll
        for (int nt = 0; nt < 4; nt++)
#pragma unroll
            for (int ks = 0; ks < 2; ks++)
                bv[nt][ks] = *(const short8*)(vbase +
                    (size_t)(nt * 16 + l16) * NSEQ + j0 + ks * 32 + quad * 8);

#pragma unroll
        for (int ri = 0; ri < 2; ri++) {
            f32x4 s[4];
#pragma unroll
            for (int jt = 0; jt < 4; jt++) s[jt] = zero;
#pragma unroll
            for (int jt = 0; jt < 4; jt++)
#pragma unroll
                for (int ks = 0; ks < 2; ks++)
                    s[jt] = __builtin_amdgcn_mfma_f32_16x16x32_bf16(
                        aq[ri][ks], bk[jt][ks], s[jt], 0, 0, 0);
            // bounded softmax: p = 2^s (s <= ~11.7); row = quad*4+rr
#pragma unroll
            for (int rr = 0; rr < 4; rr++)
#pragma unroll
                for (int jt = 0; jt < 4; jt++)
                    pw[(ri * 16 + quad * 4 + rr) * PSTR + jt * 16 + l16] =
                        __float2bfloat16(exp2f(s[jt][rr]));
        }
        // PV: A = P from wave-private LDS (compiler inserts lgkmcnt wait);
        // nt=4 uses the ones-fragment -> accumulates the row-sum.
#pragma unroll
        for (int ri = 0; ri < 2; ri++) {
            short8 ap[2];
#pragma unroll
            for (int ks = 0; ks < 2; ks++)
                ap[ks] = *(const short8*)&pw[(ri * 16 + l16) * PSTR + ks * 32 + quad * 8];
#pragma unroll
            for (int nt = 0; nt < 5; nt++)
#pragma unroll
                for (int ks = 0; ks < 2; ks++)
                    o[ri][nt] = __builtin_amdgcn_mfma_f32_16x16x32_bf16(
                        ap[ks], (nt == 4) ? bones : bv[nt][ks], o[ri][nt], 0, 0, 0);
        }
    }

#pragma unroll
    for (int ri = 0; ri < 2; ri++)
#pragma unroll
        for (int rr = 0; rr < 4; rr++) {
            // row-sum lives in lane quad*16 (output col 0) of o[ri][4][rr]
            float lsum = __shfl(o[ri][4][rr], quad << 4, 64);
            float inv = 1.f / lsum;
            int row = qrow0 + ri * 16 + quad * 4 + rr;
#pragma unroll
            for (int nt = 0; nt < 4; nt++)
                ao[((size_t)b * NSEQ + row) * CDIM + h * 64 + nt * 16 + l16] =
                    __float2bfloat16(o[ri][nt][rr] * inv);
        }
}

// ---------- attn_map: mean over heads of attn[:,0,1:] ----------
__global__ __launch_bounds__(256) void attn_map_acc(
    const __hip_bfloat16* __restrict__ qf, const __hip_bfloat16* __restrict__ kf,
    float* __restrict__ am)
{
    __shared__ float q0[64];
    __shared__ float red[256];
    int bh = blockIdx.x, t = threadIdx.x;
    const __hip_bfloat16* qr = qf + (size_t)bh * NSEQ * DHEAD;   // row 0
    const __hip_bfloat16* kb = kf + (size_t)bh * NSEQ * DHEAD;
    if (t < 64) q0[t] = __bfloat162float(qr[t]);   // q pre-scaled (0.125*log2e)
    __syncthreads();
    float s[4];
    float mx = -1e30f;
#pragma unroll
    for (int ji = 0; ji < 4; ji++) {
        int j = ji * 256 + t;
        float a = 0.f;
        for (int k = 0; k < 64; k++) a += q0[k] * __bfloat162float(kb[(size_t)j * 64 + k]);
        s[ji] = a;
        mx = fmaxf(mx, a);
    }
    red[t] = mx; __syncthreads();
    for (int st = 128; st > 0; st >>= 1) {
        if (t < st) red[t] = fmaxf(red[t], red[t + st]);
        __syncthreads();
    }
    float M = red[0]; __syncthreads();
    float sum = 0.f;
#pragma unroll
    for (int ji = 0; ji < 4; ji++) { s[ji] = exp2f(s[ji] - M); sum += s[ji]; }
    red[t] = sum; __syncthreads();
    for (int st = 128; st > 0; st >>= 1) {
        if (t < st) red[t] += red[t + st];
        __syncthreads();
    }
    float inv = 1.f / red[0];
    int b = bh >> 4;
#pragma unroll
    for (int ji = 0; ji < 4; ji++) {
        int j = ji * 256 + t;
        if (j > 0) atomicAdd(&am[b * 1024 + j], s[ji] * inv * (1.f / 16.f));
    }
}

__global__ __launch_bounds__(256) void attn_map_out(
    const float* __restrict__ am, float* __restrict__ out1)
{
    int i = blockIdx.x * 256 + threadIdx.x;
    if (i < 4 * 1023) {
        int b = i / 1023;
        int j = i - b * 1023 + 1;
        out1[i] = am[b * 1024 + j];
    }
}

// ---------- launch ----------
extern "C" void kernel_launch(void* const* d_in, const int* in_sizes, int n_in,
                              void* d_out, int out_size, void* d_ws, size_t ws_size,
                              hipStream_t stream)
{
    const float* x_list = (const float*)d_in[0];
    const float* wvec   = (const float*)d_in[1];
    const float* qkv_w  = (const float*)d_in[2];
    const float* qkv_b  = (const float*)d_in[3];
    const float* proj_w = (const float*)d_in[4];
    const float* proj_b = (const float*)d_in[5];
    const float* nq_g   = (const float*)d_in[6];
    const float* nq_b   = (const float*)d_in[7];
    const float* nk_g   = (const float*)d_in[8];
    const float* nk_b   = (const float*)d_in[9];
    const float* conv_w = (const float*)d_in[10];
    const float* conv_b = (const float*)d_in[11];
    const float* ca1_w  = (const float*)d_in[12];
    const float* ca1_b  = (const float*)d_in[13];
    const float* ca2_w  = (const float*)d_in[14];
    const float* ca2_b  = (const float*)d_in[15];
    const float* mlp1_w = (const float*)d_in[16];
    const float* mlp1_b = (const float*)d_in[17];
    const float* mlp2_w = (const float*)d_in[18];
    const float* mlp2_b = (const float*)d_in[19];

    float* out0 = (float*)d_out;
    float* out1 = out0 + (size_t)4 * 1024 * 1024;

    char* ws = (char*)d_ws;
    size_t off = 0;
    auto alloc = [&](size_t bytes) -> char* {
        char* p = ws + off;
        off += (bytes + 255) & ~(size_t)255;
        return p;
    };
    __hip_bfloat16* xb     = (__hip_bfloat16*)alloc((size_t)MROWS * CDIM * 2);
    __hip_bfloat16* xmixb  = (__hip_bfloat16*)alloc((size_t)MROWS * CDIM * 2);
    float*          h1     = (float*)alloc((size_t)MROWS * 64 * 4);
    __hip_bfloat16* hb     = (__hip_bfloat16*)alloc((size_t)MROWS * 4096 * 2);
    __hip_bfloat16* qbb    = (__hip_bfloat16*)alloc((size_t)MROWS * CDIM * 2);
    __hip_bfloat16* kbb    = (__hip_bfloat16*)alloc((size_t)MROWS * CDIM * 2);
    __hip_bfloat16* vtb    = (__hip_bfloat16*)alloc((size_t)MROWS * CDIM * 2);
    __hip_bfloat16* aob    = (__hip_bfloat16*)alloc((size_t)MROWS * CDIM * 2);
    float*          amacc  = (float*)alloc(4096 * 4);
    __hip_bfloat16* wcat   = (__hip_bfloat16*)alloc((size_t)5248 * 1024 * 2);  // conv|mlp1|ca1|pad
    __hip_bfloat16* qkvwb  = (__hip_bfloat16*)alloc((size_t)3145728 * 2);
    __hip_bfloat16* projwb = (__hip_bfloat16*)alloc((size_t)1048576 * 2);
    __hip_bfloat16* mlp2wb = (__hip_bfloat16*)alloc((size_t)4194304 * 2);

    // weight converts, one fused launch (13762560 elems / 4 / 256 = 13440 blocks)
    f2b_all<<<13440, 256, 0, stream>>>(conv_w, mlp1_w, qkv_w, proj_w, mlp2_w,
                                       ca1_w, wcat, qkvwb, projwb, mlp2wb);

    // prologue: x -> bf16 (vectorized)
    mix_base<<<8192, 256, 0, stream>>>(x_list, xb, amacc);

    // fused conv+mlp1+ca1: 1D grid 1312, order-preserving decode (SWZ=2)
    // restores the 40-wide column->XCD pinning; ca1 column appended last.
    gemm_bf16<1, 4, 4, 2><<<1312, 256, 0, stream>>>(
        xb, wcat, conv_b, h1, x_list, xmixb, hb, nullptr,
        ca1_b, mlp1_b, nullptr, nullptr, wvec, MROWS, 5248, 1024);

    // channel attention part 2: xmixb += w3*sig(h1 @ ca2_w^T + b)*x (bf16 rmw)
    ca2_kernel<<<dim3(256, 4), 256, 0, stream>>>(h1, ca2_w, ca2_b, xb, xmixb, wvec);

    // mlp2: xmixb += w5*(hb @ mlp2_w^T + b)  [64x128 tile, 512 blocks]
    gemm_bf16<3, 2, 4, 1><<<dim3(8, 64), 256, 0, stream>>>(
        hb, mlp2wb, mlp2_b, nullptr, nullptr, xmixb, nullptr, nullptr,
        nullptr, nullptr, nullptr, nullptr, wvec, MROWS, 1024, 4096);

    // qkv with fused per-head LN: q->qbb (x 0.125*log2e), k->kbb; v->V^T
    gemm_bf16<5, 4, 4, 1><<<dim3(24, 32), 256, 0, stream>>>(
        xmixb, qkvwb, qkv_b, nullptr, nullptr, vtb, qbb, kbb,
        nq_g, nq_b, nk_g, nk_b, wvec, MROWS, 3072, 1024);

    // attention (MFMA, bh-major XCD swizzle, bounded exp2 softmax, MFMA row-sum)
    flash_mfma<<<dim3(64, 8), 256, 0, stream>>>(qbb, kbb, vtb, aob);

    // attn_map
    attn_map_acc<<<64, 256, 0, stream>>>(qbb, kbb, amacc);
    attn_map_out<<<16, 256, 0, stream>>>(amacc, out1);

    // projection + residual  [64x128 tile, 512 blocks]
    gemm_bf16<4, 2, 4, 1><<<dim3(8, 64), 256, 0, stream>>>(
        aob, projwb, proj_b, out0, nullptr, nullptr, xmixb, nullptr,
        nullptr, nullptr, nullptr, nullptr, wvec, MROWS, 1024, 1024);
}

// Round 11
// 474.442 us; speedup vs baseline: 1.1938x; 1.1938x over previous
//
#include <hip/hip_runtime.h>
#include <hip/hip_bf16.h>

// ---------- types ----------
typedef __attribute__((ext_vector_type(8))) short short8;
typedef __attribute__((ext_vector_type(4))) float f32x4;

#define MROWS 4096      // b*l
#define CDIM  1024
#define HEADS 16
#define DHEAD 64
#define NSEQ  1024

// ---------- small device helpers ----------
__device__ inline float softw(const float* __restrict__ w, int idx) {
    // softmax(w/0.01)[idx] over 6 entries
    float m = w[0];
#pragma unroll
    for (int i = 1; i < 6; i++) m = fmaxf(m, w[i]);
    float s = 0.f, v = 0.f;
#pragma unroll
    for (int i = 0; i < 6; i++) {
        float e = __expf((w[i] - m) * 100.0f);
        s += e;
        if (i == idx) v = e;
    }
    return v / s;
}

__device__ inline float gelu_f(float x) {
    return 0.5f * x * (1.0f + erff(x * 0.70710678118654752f));
}

// ---------- fused prologue: all weight converts + x -> bf16 (1 launch) ----------
// blocks 0..13439: f2b. wcat row-major [5248][1024]: rows 0..1023 conv_w,
//   1024..5119 mlp1_w, 5120..5183 ca1_w, 5184..5247 zero pad.
// blocks 13440..21631: x_list -> xb (bf16, slot 1 of pairs), zero am_acc.
__global__ __launch_bounds__(256) void prep_all(
    const float* __restrict__ conv_w, const float* __restrict__ mlp1_w,
    const float* __restrict__ qkv_w, const float* __restrict__ proj_w,
    const float* __restrict__ mlp2_w, const float* __restrict__ ca1_w,
    __hip_bfloat16* __restrict__ wcat, __hip_bfloat16* __restrict__ qkvwb,
    __hip_bfloat16* __restrict__ projwb, __hip_bfloat16* __restrict__ mlp2wb,
    const float* __restrict__ x_list, __hip_bfloat16* __restrict__ xb,
    float* __restrict__ am_acc)
{
    int bid = blockIdx.x;
    if (bid >= 13440) {
        int i2 = (bid - 13440) * 256 + threadIdx.x;   // 0 .. 2M-1
        float4 v = ((const float4*)x_list)[i2];       // (x0,x1) pairs
        __hip_bfloat162 o;
        o.x = __float2bfloat16(v.y);
        o.y = __float2bfloat16(v.w);
        ((__hip_bfloat162*)xb)[i2] = o;
        if (i2 < 4096) am_acc[i2] = 0.f;
        return;
    }
    size_t e = ((size_t)bid * 256 + threadIdx.x) * 4;
    const float* src; __hip_bfloat16* dst; size_t o;
    if (e < 1048576)       { src = conv_w; dst = wcat;           o = e; }
    else if (e < 5242880)  { src = mlp1_w; dst = wcat + 1048576; o = e - 1048576; }
    else if (e < 5308416)  { src = ca1_w;  dst = wcat + 5242880; o = e - 5242880; }
    else if (e < 5373952) {
        // zero pad rows 5184..5247 (read into LDS, MFMA'd, never stored)
        __hip_bfloat162 z; z.x = __float2bfloat16(0.f); z.y = z.x;
        __hip_bfloat16* d = wcat + 5308416 + (e - 5308416);
        *(__hip_bfloat162*)(d)     = z;
        *(__hip_bfloat162*)(d + 2) = z;
        return;
    }
    else if (e < 8519680)  { src = qkv_w;  dst = qkvwb;          o = e - 5373952; }
    else if (e < 9568256)  { src = proj_w; dst = projwb;         o = e - 8519680; }
    else                   { src = mlp2_w; dst = mlp2wb;         o = e - 9568256; }
    float4 v = *(const float4*)(src + o);
    __hip_bfloat162 a, b;
    a.x = __float2bfloat16(v.x); a.y = __float2bfloat16(v.y);
    b.x = __float2bfloat16(v.z); b.y = __float2bfloat16(v.w);
    *(__hip_bfloat162*)(dst + o)     = a;
    *(__hip_bfloat162*)(dst + o + 2) = b;
}

// ---------- bf16 MFMA GEMM, dbuf LDS + depth-2 register prefetch ----------
// Verified-fast 2-phase core. EPI=1 is the in-run environment control
// (~100-106 us healthy; degraded nodes inflate 15-75%).
// SWZ=0: natural 2D. SWZ=1: XCD row-chunk remap (mlp2/qkv/proj).
// SWZ=2: EPI=1 only -- 1D grid of 1312; blocks 0..1279 use the exact 40-wide
//   x-fastest map (XCD = bx%8 pinning: B/x_list panels stay in one L2 each;
//   round-8's 41-wide grid broke this, FETCH 61->182 MB; SWZ=2 restored it,
//   FETCH ~65 MB confirmed round 10), ca1/pad column (bx=40) appended last.
// EPI: 1=fused conv+mlp1+ca1, 3=mlp2 rmw, 4=proj+residual,
//      5=qkv+per-head LN (q gain x 0.125*log2e: folds 1/sqrt(d) AND the
//        exp->exp2 conversion for flash/attn_map; exact softmax invariance).
#define BKT 32
#define LDA 40   // 32 + 8 pad (16B aligned rows: 80 B; 2-way LDS banks = free)

template<int EPI, int FM, int FN, int SWZ>
__global__ __launch_bounds__(256) void gemm_bf16(
    const __hip_bfloat16* __restrict__ A, const __hip_bfloat16* __restrict__ W,
    const float* __restrict__ bias,
    float* __restrict__ f0, const float* __restrict__ f1,
    __hip_bfloat16* __restrict__ b0, __hip_bfloat16* __restrict__ b1,
    __hip_bfloat16* __restrict__ b2,
    const float* __restrict__ g0, const float* __restrict__ be0,
    const float* __restrict__ g1, const float* __restrict__ be1,
    const float* __restrict__ wvec, int M, int N, int K)
{
    constexpr int BMt = FM * 32;
    constexpr int BNt = FN * 32;
    constexpr int NA = BMt / 64;    // short8 staged per thread (A)
    constexpr int NB = BNt / 64;    // short8 staged per thread (B)
    __shared__ __hip_bfloat16 As[2][BMt * LDA];
    __shared__ __hip_bfloat16 Bs[2][BNt * LDA];
    int t = threadIdx.x;
    int bx = blockIdx.x, by = blockIdx.y;
    if constexpr (SWZ == 1) {
        // bijective XCD remap; requires nwg % 8 == 0
        int nx = gridDim.x;
        int lin = by * nx + bx;
        int cpx = (nx * gridDim.y) >> 3;
        int swz = (lin & 7) * cpx + (lin >> 3);
        bx = swz % nx;
        by = swz / nx;
    }
    if constexpr (SWZ == 2) {
        int l = blockIdx.x;          // 1D grid of 1312
        if (l < 1280) { bx = l % 40; by = l / 40; }  // original pinned map
        else          { bx = 40;     by = l - 1280; } // ca1+pad column, last
    }
    int n0 = bx * BNt, m0 = by * BMt;
    int wave = t >> 6, lane = t & 63;
    int wr = wave >> 1, wc = wave & 1;
    int quad = lane >> 4, l16 = lane & 15;
    int r0 = t >> 2, c0 = (t & 3) * 8;    // staging: 4 lanes/row, 64 rows/round

    short8 sa0[NA], sb0[NB], sa1[NA], sb1[NB];
    auto ldg = [&](int k0, short8* da, short8* db) {
#pragma unroll
        for (int i = 0; i < NA; i++)
            da[i] = *(const short8*)(A + (size_t)(m0 + r0 + 64 * i) * K + k0 + c0);
#pragma unroll
        for (int i = 0; i < NB; i++)
            db[i] = *(const short8*)(W + (size_t)(n0 + r0 + 64 * i) * K + k0 + c0);
    };
    ldg(0, sa0, sb0);
    ldg(BKT, sa1, sb1);

    f32x4 zero = {0.f, 0.f, 0.f, 0.f};
    f32x4 acc[FM][FN];
#pragma unroll
    for (int i = 0; i < FM; i++)
#pragma unroll
        for (int j = 0; j < FN; j++) acc[i][j] = zero;

    for (int k0 = 0; k0 < K; k0 += 2 * BKT) {
        // ---- even half: buffer 0 ----
#pragma unroll
        for (int i = 0; i < NA; i++)
            *(short8*)&As[0][(r0 + 64 * i) * LDA + c0] = sa0[i];
#pragma unroll
        for (int i = 0; i < NB; i++)
            *(short8*)&Bs[0][(r0 + 64 * i) * LDA + c0] = sb0[i];
        __syncthreads();
        if (k0 + 2 * BKT < K) ldg(k0 + 2 * BKT, sa0, sb0);
        {
            short8 af[FM], bf[FN];
#pragma unroll
            for (int i = 0; i < FM; i++)
                af[i] = *(const short8*)&As[0][(wr * FM * 16 + i * 16 + l16) * LDA + quad * 8];
#pragma unroll
            for (int j = 0; j < FN; j++)
                bf[j] = *(const short8*)&Bs[0][(wc * FN * 16 + j * 16 + l16) * LDA + quad * 8];
#pragma unroll
            for (int i = 0; i < FM; i++)
#pragma unroll
                for (int j = 0; j < FN; j++)
                    acc[i][j] = __builtin_amdgcn_mfma_f32_16x16x32_bf16(
                        af[i], bf[j], acc[i][j], 0, 0, 0);
        }
        // ---- odd half: buffer 1 ----
#pragma unroll
        for (int i = 0; i < NA; i++)
            *(short8*)&As[1][(r0 + 64 * i) * LDA + c0] = sa1[i];
#pragma unroll
        for (int i = 0; i < NB; i++)
            *(short8*)&Bs[1][(r0 + 64 * i) * LDA + c0] = sb1[i];
        __syncthreads();
        if (k0 + 3 * BKT < K) ldg(k0 + 3 * BKT, sa1, sb1);
        {
            short8 af[FM], bf[FN];
#pragma unroll
            for (int i = 0; i < FM; i++)
                af[i] = *(const short8*)&As[1][(wr * FM * 16 + i * 16 + l16) * LDA + quad * 8];
#pragma unroll
            for (int j = 0; j < FN; j++)
                bf[j] = *(const short8*)&Bs[1][(wc * FN * 16 + j * 16 + l16) * LDA + quad * 8];
#pragma unroll
            for (int i = 0; i < FM; i++)
#pragma unroll
                for (int j = 0; j < FN; j++)
                    acc[i][j] = __builtin_amdgcn_mfma_f32_16x16x32_bf16(
                        af[i], bf[j], acc[i][j], 0, 0, 0);
        }
    }

    if constexpr (EPI == 1) {
        // fused conv (cols 0..1023) + mlp1 (1024..5119) + ca1 (5120..5183) +
        // pad (5184..5247, skip). All boundaries 64-aligned -> wave-uniform.
        float wmx = softw(wvec, 2);
        float w0c = softw(wvec, 0);
        float w14c = softw(wvec, 1) + softw(wvec, 4);
        int colbase = n0 + wc * FN * 16;
        int region = (colbase < 1024) ? 0 : (colbase < 5120) ? 1
                   : (colbase < 5184) ? 2 : 3;
        if (region == 3) return;   // padding columns
#pragma unroll
        for (int i = 0; i < FM; i++) {
#pragma unroll
            for (int j = 0; j < FN; j++) {
                int col = colbase + j * 16 + l16;
                float bv = (region == 0) ? bias[col]
                         : (region == 1) ? be0[col - 1024]
                                         : g0[col - 5120];   // ca1_b
#pragma unroll
                for (int r = 0; r < 4; r++) {
                    int row = m0 + wr * FM * 16 + i * 16 + quad * 4 + r;
                    float v = acc[i][j][r] + bv;
                    if (region == 0) {
                        size_t idx = (size_t)row * 1024 + col;
                        float2 xl = ((const float2*)f1)[idx];
                        b0[idx] = __float2bfloat16(
                            w0c * xl.x + w14c * xl.y + wmx * gelu_f(v));
                    } else if (region == 1) {
                        b1[(size_t)row * 4096 + (col - 1024)] =
                            __float2bfloat16(gelu_f(v));
                    } else {
                        // ca1: h1 = relu(x @ ca1_w^T + b), f32
                        f0[(size_t)row * 64 + (col - 5120)] = fmaxf(v, 0.f);
                    }
                }
            }
        }
        return;
    }

    if constexpr (EPI == 5) {
        int colbase = n0 + wc * FN * 16;           // 64-aligned => one head per wave
        int portion = colbase >> 10;               // 0=q 1=k 2=v
        int hh = (colbase >> 6) & 15;
        float bv[FN];
#pragma unroll
        for (int j = 0; j < FN; j++) bv[j] = bias[colbase + j * 16 + l16];
        if (portion == 2) {
#pragma unroll
            for (int i = 0; i < FM; i++)
#pragma unroll
                for (int j = 0; j < FN; j++)
#pragma unroll
                    for (int r = 0; r < 4; r++) {
                        int row = m0 + wr * FM * 16 + i * 16 + quad * 4 + r;
                        int bb = row >> 10, nn = row & 1023;
                        int dd = j * 16 + l16;
                        b0[((size_t)(bb * 16 + hh) * DHEAD + dd) * NSEQ + nn] =
                            __float2bfloat16(acc[i][j][r] + bv[j]);
                    }
        } else {
            const float* g  = (portion == 0) ? g0 : g1;
            const float* be = (portion == 0) ? be0 : be1;
            __hip_bfloat16* dst = (portion == 0) ? b1 : b2;
            // q gain: 1/sqrt(d)=0.125 AND log2(e) (flash/attn_map use exp2)
            float qs = (portion == 0) ? 0.125f * 1.4426950408889634f : 1.0f;
            float gv[FN], bev[FN];
#pragma unroll
            for (int j = 0; j < FN; j++) {
                gv[j] = g[j * 16 + l16] * qs;
                bev[j] = be[j * 16 + l16] * qs;
            }
#pragma unroll
            for (int i = 0; i < FM; i++)
#pragma unroll
                for (int r = 0; r < 4; r++) {
                    float s1 = 0.f, s2 = 0.f;
#pragma unroll
                    for (int j = 0; j < FN; j++) {
                        float v = acc[i][j][r] + bv[j];
                        s1 += v; s2 += v * v;
                    }
#pragma unroll
                    for (int mk = 1; mk < 16; mk <<= 1) {
                        s1 += __shfl_xor(s1, mk, 64);
                        s2 += __shfl_xor(s2, mk, 64);
                    }
                    float mean = s1 * (1.f / 64.f);
                    float var = s2 * (1.f / 64.f) - mean * mean;
                    float rs = rsqrtf(var + 1e-5f);
                    int row = m0 + wr * FM * 16 + i * 16 + quad * 4 + r;
                    int bb = row >> 10, nn = row & 1023;
                    size_t base = ((size_t)(bb * 16 + hh) * NSEQ + nn) * DHEAD;
#pragma unroll
                    for (int j = 0; j < FN; j++)
                        dst[base + j * 16 + l16] = __float2bfloat16(
                            (acc[i][j][r] + bv[j] - mean) * rs * gv[j] + bev[j]);
                }
        }
        return;
    }

    float wmx = 0.f;
    if (EPI == 3) wmx = softw(wvec, 5);

#pragma unroll
    for (int i = 0; i < FM; i++) {
#pragma unroll
        for (int j = 0; j < FN; j++) {
            int col = n0 + wc * FN * 16 + j * 16 + l16;
            float bv = bias[col];
#pragma unroll
            for (int r = 0; r < 4; r++) {
                int row = m0 + wr * FM * 16 + i * 16 + quad * 4 + r;
                float v = acc[i][j][r] + bv;
                size_t idx = (size_t)row * N + col;
                if (EPI == 3) {
                    // final mix: xmixb += w5 * v (bf16 rmw)
                    float tv = __bfloat162float(b0[idx]) + wmx * v;
                    b0[idx] = __float2bfloat16(tv);
                } else if (EPI == 4) {
                    f0[idx] = v + __bfloat162float(b1[idx]);  // proj + residual
                }
            }
        }
    }
}

// ---------- ca2: xmixb += w3 * sigmoid(h1 @ ca2_w^T + b) * x  (bf16 rmw) ----------
__global__ __launch_bounds__(256) void ca2_kernel(
    const float* __restrict__ h1, const float* __restrict__ w,
    const float* __restrict__ bias, const __hip_bfloat16* __restrict__ xb,
    __hip_bfloat16* __restrict__ xmixb, const float* __restrict__ wvec)
{
    __shared__ float Wt[256 * 65];
    __shared__ float hs[16 * 64];
    int t = threadIdx.x;
    int m0 = blockIdx.x * 16, n0 = blockIdx.y * 256;
#pragma unroll
    for (int i = 0; i < 64; i++) {
        int e = t + i * 256; int r = e >> 6, c = e & 63;
        Wt[r * 65 + c] = w[(size_t)(n0 + r) * 64 + c];
    }
#pragma unroll
    for (int i = 0; i < 4; i++) {
        int e = t + i * 256; int r = e >> 6, c = e & 63;
        hs[r * 64 + c] = h1[(size_t)(m0 + r) * 64 + c];
    }
    __syncthreads();
    int n = n0 + t;
    float bv = bias[n];
    float acc[16];
#pragma unroll
    for (int mi = 0; mi < 16; mi++) acc[mi] = bv;
    for (int k = 0; k < 64; k++) {
        float wv = Wt[t * 65 + k];
#pragma unroll
        for (int mi = 0; mi < 16; mi++) acc[mi] += hs[mi * 64 + k] * wv;
    }
    float w3 = softw(wvec, 3);
#pragma unroll
    for (int mi = 0; mi < 16; mi++) {
        size_t idx = (size_t)(m0 + mi) * 1024 + n;
        float sg = 1.f / (1.f + __expf(-acc[mi]));
        float cur = __bfloat162float(xmixb[idx]);
        xmixb[idx] = __float2bfloat16(cur + w3 * sg * __bfloat162float(xb[idx]));
    }
}

// ---------- MFMA flash attention ----------
// grid (64 bh, 8 i-tiles), block 256 (4 waves). Wave owns 32 q-rows.
// XCD swizzle (T1): XCD k serves heads 8k..8k+7 -> K/V L2-resident per XCD.
// BOUNDED softmax (q,k LayerNormed => |s| <= 8*log2e): p = 2^s directly,
// no running max (exact; q carries 0.125*log2e from qkv epilogue).
// ROW-SUM VIA MFMA: synthetic ones-fragment (l16==0 lanes = bf16(1.0)) as a
// 5th PV B-tile -> o[ri][4] accumulates sum_j p in the l16==0 lanes; replaces
// the per-j-tile shfl_xor reduction (~100 VALU cyc) with 4 MFMA + 8 final shfl.
#define PSTR 72   // bf16 stride: 144 B, 16B-aligned, 2-way banks
__global__ __launch_bounds__(256) void flash_mfma(
    const __hip_bfloat16* __restrict__ qb, const __hip_bfloat16* __restrict__ kb,
    const __hip_bfloat16* __restrict__ vt, __hip_bfloat16* __restrict__ ao)
{
    __shared__ __hip_bfloat16 Plds[4][32 * PSTR];
    int l = blockIdx.y * 64 + blockIdx.x;      // hw linear id (x fastest)
    int swz = (l & 7) * 64 + (l >> 3);         // bijection on [0,512)
    int bh = swz >> 3;
    int i0 = (swz & 7) * 128;
    int b = bh >> 4, h = bh & 15;
    int t = threadIdx.x, wave = t >> 6, lane = t & 63;
    int l16 = lane & 15, quad = lane >> 4;
    const __hip_bfloat16* qbase = qb + (size_t)bh * NSEQ * DHEAD;
    const __hip_bfloat16* kbase = kb + (size_t)bh * NSEQ * DHEAD;
    const __hip_bfloat16* vbase = vt + (size_t)bh * DHEAD * NSEQ;
    __hip_bfloat16* pw = Plds[wave];
    int qrow0 = i0 + wave * 32;

    // Q fragments, held for the whole kernel (pre-scaled in qkv epi)
    short8 aq[2][2];
#pragma unroll
    for (int ri = 0; ri < 2; ri++)
#pragma unroll
        for (int ks = 0; ks < 2; ks++)
            aq[ri][ks] = *(const short8*)(qbase +
                (size_t)(qrow0 + ri * 16 + l16) * DHEAD + ks * 32 + quad * 8);

    // ones-fragment: B row 64 == 1.0 (lanes l16==0), rows 65..79 == 0
    short8 bones;
    {
        short fill = (l16 == 0) ? (short)0x3F80 : (short)0;
#pragma unroll
        for (int z = 0; z < 8; z++) bones[z] = fill;
    }

    f32x4 zero = {0.f, 0.f, 0.f, 0.f};
    f32x4 o[2][5];                 // [..][4] = row-sum accumulator
#pragma unroll
    for (int ri = 0; ri < 2; ri++)
#pragma unroll
        for (int nt = 0; nt < 5; nt++) o[ri][nt] = zero;

    for (int j0 = 0; j0 < NSEQ; j0 += 64) {
        // K fragments: B[n=key][k=d]
        short8 bk[4][2];
#pragma unroll
        for (int jt = 0; jt < 4; jt++)
#pragma unroll
            for (int ks = 0; ks < 2; ks++)
                bk[jt][ks] = *(const short8*)(kbase +
                    (size_t)(j0 + jt * 16 + l16) * DHEAD + ks * 32 + quad * 8);
        // V^T fragments: B[n=d][k=key]
        short8 bv[4][2];
#pragma unroll
        for (int nt = 0; nt < 4; nt++)
#pragma unroll
            for (int ks = 0; ks < 2; ks++)
                bv[nt][ks] = *(const short8*)(vbase +
                    (size_t)(nt * 16 + l16) * NSEQ + j0 + ks * 32 + quad * 8);

#pragma unroll
        for (int ri = 0; ri < 2; ri++) {
            f32x4 s[4];
#pragma unroll
            for (int jt = 0; jt < 4; jt++) s[jt] = zero;
#pragma unroll
            for (int jt = 0; jt < 4; jt++)
#pragma unroll
                for (int ks = 0; ks < 2; ks++)
                    s[jt] = __builtin_amdgcn_mfma_f32_16x16x32_bf16(
                        aq[ri][ks], bk[jt][ks], s[jt], 0, 0, 0);
            // bounded softmax: p = 2^s (s <= ~11.7); row = quad*4+rr
#pragma unroll
            for (int rr = 0; rr < 4; rr++)
#pragma unroll
                for (int jt = 0; jt < 4; jt++)
                    pw[(ri * 16 + quad * 4 + rr) * PSTR + jt * 16 + l16] =
                        __float2bfloat16(exp2f(s[jt][rr]));
        }
        // PV: A = P from wave-private LDS (compiler inserts lgkmcnt wait);
        // nt=4 uses the ones-fragment -> accumulates the row-sum.
#pragma unroll
        for (int ri = 0; ri < 2; ri++) {
            short8 ap[2];
#pragma unroll
            for (int ks = 0; ks < 2; ks++)
                ap[ks] = *(const short8*)&pw[(ri * 16 + l16) * PSTR + ks * 32 + quad * 8];
#pragma unroll
            for (int nt = 0; nt < 5; nt++)
#pragma unroll
                for (int ks = 0; ks < 2; ks++)
                    o[ri][nt] = __builtin_amdgcn_mfma_f32_16x16x32_bf16(
                        ap[ks], (nt == 4) ? bones : bv[nt][ks], o[ri][nt], 0, 0, 0);
        }
    }

#pragma unroll
    for (int ri = 0; ri < 2; ri++)
#pragma unroll
        for (int rr = 0; rr < 4; rr++) {
            // row-sum lives in lane quad*16 (output col 0) of o[ri][4][rr]
            float lsum = __shfl(o[ri][4][rr], quad << 4, 64);
            float inv = 1.f / lsum;
            int row = qrow0 + ri * 16 + quad * 4 + rr;
#pragma unroll
            for (int nt = 0; nt < 4; nt++)
                ao[((size_t)b * NSEQ + row) * CDIM + h * 64 + nt * 16 + l16] =
                    __float2bfloat16(o[ri][nt][rr] * inv);
        }
}

// ---------- attn_map: mean over heads of attn[:,0,1:] ----------
__global__ __launch_bounds__(256) void attn_map_acc(
    const __hip_bfloat16* __restrict__ qf, const __hip_bfloat16* __restrict__ kf,
    float* __restrict__ am)
{
    __shared__ float q0[64];
    __shared__ float red[256];
    int bh = blockIdx.x, t = threadIdx.x;
    const __hip_bfloat16* qr = qf + (size_t)bh * NSEQ * DHEAD;   // row 0
    const __hip_bfloat16* kb = kf + (size_t)bh * NSEQ * DHEAD;
    if (t < 64) q0[t] = __bfloat162float(qr[t]);   // q pre-scaled (0.125*log2e)
    __syncthreads();
    float s[4];
    float mx = -1e30f;
#pragma unroll
    for (int ji = 0; ji < 4; ji++) {
        int j = ji * 256 + t;
        float a = 0.f;
        for (int k = 0; k < 64; k++) a += q0[k] * __bfloat162float(kb[(size_t)j * 64 + k]);
        s[ji] = a;
        mx = fmaxf(mx, a);
    }
    red[t] = mx; __syncthreads();
    for (int st = 128; st > 0; st >>= 1) {
        if (t < st) red[t] = fmaxf(red[t], red[t + st]);
        __syncthreads();
    }
    float M = red[0]; __syncthreads();
    float sum = 0.f;
#pragma unroll
    for (int ji = 0; ji < 4; ji++) { s[ji] = exp2f(s[ji] - M); sum += s[ji]; }
    red[t] = sum; __syncthreads();
    for (int st = 128; st > 0; st >>= 1) {
        if (t < st) red[t] += red[t + st];
        __syncthreads();
    }
    float inv = 1.f / red[0];
    int b = bh >> 4;
#pragma unroll
    for (int ji = 0; ji < 4; ji++) {
        int j = ji * 256 + t;
        if (j > 0) atomicAdd(&am[b * 1024 + j], s[ji] * inv * (1.f / 16.f));
    }
}

__global__ __launch_bounds__(256) void attn_map_out(
    const float* __restrict__ am, float* __restrict__ out1)
{
    int i = blockIdx.x * 256 + threadIdx.x;
    if (i < 4 * 1023) {
        int b = i / 1023;
        int j = i - b * 1023 + 1;
        out1[i] = am[b * 1024 + j];
    }
}

// ---------- launch ----------
extern "C" void kernel_launch(void* const* d_in, const int* in_sizes, int n_in,
                              void* d_out, int out_size, void* d_ws, size_t ws_size,
                              hipStream_t stream)
{
    const float* x_list = (const float*)d_in[0];
    const float* wvec   = (const float*)d_in[1];
    const float* qkv_w  = (const float*)d_in[2];
    const float* qkv_b  = (const float*)d_in[3];
    const float* proj_w = (const float*)d_in[4];
    const float* proj_b = (const float*)d_in[5];
    const float* nq_g   = (const float*)d_in[6];
    const float* nq_b   = (const float*)d_in[7];
    const float* nk_g   = (const float*)d_in[8];
    const float* nk_b   = (const float*)d_in[9];
    const float* conv_w = (const float*)d_in[10];
    const float* conv_b = (const float*)d_in[11];
    const float* ca1_w  = (const float*)d_in[12];
    const float* ca1_b  = (const float*)d_in[13];
    const float* ca2_w  = (const float*)d_in[14];
    const float* ca2_b  = (const float*)d_in[15];
    const float* mlp1_w = (const float*)d_in[16];
    const float* mlp1_b = (const float*)d_in[17];
    const float* mlp2_w = (const float*)d_in[18];
    const float* mlp2_b = (const float*)d_in[19];

    float* out0 = (float*)d_out;
    float* out1 = out0 + (size_t)4 * 1024 * 1024;

    char* ws = (char*)d_ws;
    size_t off = 0;
    auto alloc = [&](size_t bytes) -> char* {
        char* p = ws + off;
        off += (bytes + 255) & ~(size_t)255;
        return p;
    };
    __hip_bfloat16* xb     = (__hip_bfloat16*)alloc((size_t)MROWS * CDIM * 2);
    __hip_bfloat16* xmixb  = (__hip_bfloat16*)alloc((size_t)MROWS * CDIM * 2);
    float*          h1     = (float*)alloc((size_t)MROWS * 64 * 4);
    __hip_bfloat16* hb     = (__hip_bfloat16*)alloc((size_t)MROWS * 4096 * 2);
    __hip_bfloat16* qbb    = (__hip_bfloat16*)alloc((size_t)MROWS * CDIM * 2);
    __hip_bfloat16* kbb    = (__hip_bfloat16*)alloc((size_t)MROWS * CDIM * 2);
    __hip_bfloat16* vtb    = (__hip_bfloat16*)alloc((size_t)MROWS * CDIM * 2);
    __hip_bfloat16* aob    = (__hip_bfloat16*)alloc((size_t)MROWS * CDIM * 2);
    float*          amacc  = (float*)alloc(4096 * 4);
    __hip_bfloat16* wcat   = (__hip_bfloat16*)alloc((size_t)5248 * 1024 * 2);  // conv|mlp1|ca1|pad
    __hip_bfloat16* qkvwb  = (__hip_bfloat16*)alloc((size_t)3145728 * 2);
    __hip_bfloat16* projwb = (__hip_bfloat16*)alloc((size_t)1048576 * 2);
    __hip_bfloat16* mlp2wb = (__hip_bfloat16*)alloc((size_t)4194304 * 2);

    // fused prologue: all weight converts + x -> bf16 (13440 + 8192 blocks)
    prep_all<<<21632, 256, 0, stream>>>(conv_w, mlp1_w, qkv_w, proj_w, mlp2_w,
                                        ca1_w, wcat, qkvwb, projwb, mlp2wb,
                                        x_list, xb, amacc);

    // fused conv+mlp1+ca1: 1D grid 1312, order-preserving decode (SWZ=2)
    // restores the 40-wide column->XCD pinning; ca1 column appended last.
    gemm_bf16<1, 4, 4, 2><<<1312, 256, 0, stream>>>(
        xb, wcat, conv_b, h1, x_list, xmixb, hb, nullptr,
        ca1_b, mlp1_b, nullptr, nullptr, wvec, MROWS, 5248, 1024);

    // channel attention part 2: xmixb += w3*sig(h1 @ ca2_w^T + b)*x (bf16 rmw)
    ca2_kernel<<<dim3(256, 4), 256, 0, stream>>>(h1, ca2_w, ca2_b, xb, xmixb, wvec);

    // mlp2: xmixb += w5*(hb @ mlp2_w^T + b)  [64x128 tile, 512 blocks]
    gemm_bf16<3, 2, 4, 1><<<dim3(8, 64), 256, 0, stream>>>(
        hb, mlp2wb, mlp2_b, nullptr, nullptr, xmixb, nullptr, nullptr,
        nullptr, nullptr, nullptr, nullptr, wvec, MROWS, 1024, 4096);

    // qkv with fused per-head LN: q->qbb (x 0.125*log2e), k->kbb; v->V^T
    gemm_bf16<5, 4, 4, 1><<<dim3(24, 32), 256, 0, stream>>>(
        xmixb, qkvwb, qkv_b, nullptr, nullptr, vtb, qbb, kbb,
        nq_g, nq_b, nk_g, nk_b, wvec, MROWS, 3072, 1024);

    // attention (MFMA, bh-major XCD swizzle, bounded exp2 softmax, MFMA row-sum)
    flash_mfma<<<dim3(64, 8), 256, 0, stream>>>(qbb, kbb, vtb, aob);

    // attn_map
    attn_map_acc<<<64, 256, 0, stream>>>(qbb, kbb, amacc);
    attn_map_out<<<16, 256, 0, stream>>>(amacc, out1);

    // projection + residual  [64x128 tile, 512 blocks]
    gemm_bf16<4, 2, 4, 1><<<dim3(8, 64), 256, 0, stream>>>(
        aob, projwb, proj_b, out0, nullptr, nullptr, xmixb, nullptr,
        nullptr, nullptr, nullptr, nullptr, wvec, MROWS, 1024, 1024);
}

// Round 12
// 456.345 us; speedup vs baseline: 1.2411x; 1.0397x over previous
//
#include <hip/hip_runtime.h>
#include <hip/hip_bf16.h>

// ---------- types ----------
typedef __attribute__((ext_vector_type(8))) short short8;
typedef __attribute__((ext_vector_type(4))) float f32x4;

#define MROWS 4096      // b*l
#define CDIM  1024
#define HEADS 16
#define DHEAD 64
#define NSEQ  1024

// ---------- small device helpers ----------
__device__ inline float softw(const float* __restrict__ w, int idx) {
    // softmax(w/0.01)[idx] over 6 entries
    float m = w[0];
#pragma unroll
    for (int i = 1; i < 6; i++) m = fmaxf(m, w[i]);
    float s = 0.f, v = 0.f;
#pragma unroll
    for (int i = 0; i < 6; i++) {
        float e = __expf((w[i] - m) * 100.0f);
        s += e;
        if (i == idx) v = e;
    }
    return v / s;
}

__device__ inline float gelu_f(float x) {
    return 0.5f * x * (1.0f + erff(x * 0.70710678118654752f));
}

// ---------- fused prologue: all weight converts + x -> bf16 (1 launch) ----------
// blocks 0..13439: f2b. wcat row-major [5248][1024]: rows 0..1023 conv_w,
//   1024..5119 mlp1_w, 5120..5183 ca1_w, 5184..5247 zero pad.
// blocks 13440..21631: x_list -> xb (bf16, slot 1 of pairs), zero am_acc.
__global__ __launch_bounds__(256) void prep_all(
    const float* __restrict__ conv_w, const float* __restrict__ mlp1_w,
    const float* __restrict__ qkv_w, const float* __restrict__ proj_w,
    const float* __restrict__ mlp2_w, const float* __restrict__ ca1_w,
    __hip_bfloat16* __restrict__ wcat, __hip_bfloat16* __restrict__ qkvwb,
    __hip_bfloat16* __restrict__ projwb, __hip_bfloat16* __restrict__ mlp2wb,
    const float* __restrict__ x_list, __hip_bfloat16* __restrict__ xb,
    float* __restrict__ am_acc)
{
    int bid = blockIdx.x;
    if (bid >= 13440) {
        int i2 = (bid - 13440) * 256 + threadIdx.x;   // 0 .. 2M-1
        float4 v = ((const float4*)x_list)[i2];       // (x0,x1) pairs
        __hip_bfloat162 o;
        o.x = __float2bfloat16(v.y);
        o.y = __float2bfloat16(v.w);
        ((__hip_bfloat162*)xb)[i2] = o;
        if (i2 < 4096) am_acc[i2] = 0.f;
        return;
    }
    size_t e = ((size_t)bid * 256 + threadIdx.x) * 4;
    const float* src; __hip_bfloat16* dst; size_t o;
    if (e < 1048576)       { src = conv_w; dst = wcat;           o = e; }
    else if (e < 5242880)  { src = mlp1_w; dst = wcat + 1048576; o = e - 1048576; }
    else if (e < 5308416)  { src = ca1_w;  dst = wcat + 5242880; o = e - 5242880; }
    else if (e < 5373952) {
        // zero pad rows 5184..5247 (read into LDS, MFMA'd, never stored)
        __hip_bfloat162 z; z.x = __float2bfloat16(0.f); z.y = z.x;
        __hip_bfloat16* d = wcat + 5308416 + (e - 5308416);
        *(__hip_bfloat162*)(d)     = z;
        *(__hip_bfloat162*)(d + 2) = z;
        return;
    }
    else if (e < 8519680)  { src = qkv_w;  dst = qkvwb;          o = e - 5373952; }
    else if (e < 9568256)  { src = proj_w; dst = projwb;         o = e - 8519680; }
    else                   { src = mlp2_w; dst = mlp2wb;         o = e - 9568256; }
    float4 v = *(const float4*)(src + o);
    __hip_bfloat162 a, b;
    a.x = __float2bfloat16(v.x); a.y = __float2bfloat16(v.y);
    b.x = __float2bfloat16(v.z); b.y = __float2bfloat16(v.w);
    *(__hip_bfloat162*)(dst + o)     = a;
    *(__hip_bfloat162*)(dst + o + 2) = b;
}

// ---------- bf16 MFMA GEMM, dbuf LDS + depth-2 register prefetch ----------
// Verified-fast 2-phase core. EPI=1 is the in-run environment control
// (~102-110 us healthy; degraded nodes inflate 15-75%).
// BK: K-tile per LDS buffer (32 default; 64 for mlp2's K=4096 -> half the
//   barrier-drain count; FM=2 keeps LDS at 55.3 KB, 2 blocks/CU unchanged).
// SWZ=0: natural 2D. SWZ=1: XCD row-chunk remap (mlp2/qkv/proj).
// SWZ=2: EPI=1 only -- 1D grid of 1312. Blocks 0..31 = ca1/pad column
//   (PREPENDED: fills the first occupancy round instead of a serial tail;
//   32 % 8 == 0 so the main blocks' dispatch-index mod 8 -> XCD pinning is
//   unchanged). Blocks 32..1311 = exact 40-wide x-fastest map (XCD = bx%8
//   pinning; FETCH ~65 MB confirmed round 10).
// EPI: 1=fused conv+mlp1+ca1, 3=mlp2 rmw, 4=proj+residual,
//      5=qkv+per-head LN (q gain x 0.125*log2e: folds 1/sqrt(d) AND the
//        exp->exp2 conversion for flash/attn_map; exact softmax invariance).
template<int EPI, int FM, int FN, int SWZ, int BK>
__global__ __launch_bounds__(256) void gemm_bf16(
    const __hip_bfloat16* __restrict__ A, const __hip_bfloat16* __restrict__ W,
    const float* __restrict__ bias,
    float* __restrict__ f0, const float* __restrict__ f1,
    __hip_bfloat16* __restrict__ b0, __hip_bfloat16* __restrict__ b1,
    __hip_bfloat16* __restrict__ b2,
    const float* __restrict__ g0, const float* __restrict__ be0,
    const float* __restrict__ g1, const float* __restrict__ be1,
    const float* __restrict__ wvec, int M, int N, int K)
{
    constexpr int BMt = FM * 32;
    constexpr int BNt = FN * 32;
    constexpr int LDAx = BK + 8;     // row pitch (elems); 16B-aligned rows
    constexpr int LPR = BK / 8;      // lanes per staged row
    constexpr int RPR = 256 / LPR;   // rows staged per 256-thread round
    constexpr int NA = BMt / RPR;    // short8 staged per thread (A)
    constexpr int NB = BNt / RPR;    // short8 staged per thread (B)
    __shared__ __hip_bfloat16 As[2][BMt * LDAx];
    __shared__ __hip_bfloat16 Bs[2][BNt * LDAx];
    int t = threadIdx.x;
    int bx = blockIdx.x, by = blockIdx.y;
    if constexpr (SWZ == 1) {
        // bijective XCD remap; requires nwg % 8 == 0
        int nx = gridDim.x;
        int lin = by * nx + bx;
        int cpx = (nx * gridDim.y) >> 3;
        int swz = (lin & 7) * cpx + (lin >> 3);
        bx = swz % nx;
        by = swz / nx;
    }
    if constexpr (SWZ == 2) {
        int l = blockIdx.x;          // 1D grid of 1312
        if (l < 32) { bx = 40; by = l; }                   // ca1+pad col, FIRST
        else { int l2 = l - 32; bx = l2 % 40; by = l2 / 40; }  // pinned map
    }
    int n0 = bx * BNt, m0 = by * BMt;
    int wave = t >> 6, lane = t & 63;
    int wr = wave >> 1, wc = wave & 1;
    int quad = lane >> 4, l16 = lane & 15;
    int r0 = t / LPR, c0 = (t % LPR) * 8;   // staging decomposition

    short8 sa0[NA], sb0[NB], sa1[NA], sb1[NB];
    auto ldg = [&](int k0, short8* da, short8* db) {
#pragma unroll
        for (int i = 0; i < NA; i++)
            da[i] = *(const short8*)(A + (size_t)(m0 + r0 + RPR * i) * K + k0 + c0);
#pragma unroll
        for (int i = 0; i < NB; i++)
            db[i] = *(const short8*)(W + (size_t)(n0 + r0 + RPR * i) * K + k0 + c0);
    };
    ldg(0, sa0, sb0);
    ldg(BK, sa1, sb1);

    f32x4 zero = {0.f, 0.f, 0.f, 0.f};
    f32x4 acc[FM][FN];
#pragma unroll
    for (int i = 0; i < FM; i++)
#pragma unroll
        for (int j = 0; j < FN; j++) acc[i][j] = zero;

    auto store_lds = [&](int bufi, short8* da, short8* db) {
#pragma unroll
        for (int i = 0; i < NA; i++)
            *(short8*)&As[bufi][(r0 + RPR * i) * LDAx + c0] = da[i];
#pragma unroll
        for (int i = 0; i < NB; i++)
            *(short8*)&Bs[bufi][(r0 + RPR * i) * LDAx + c0] = db[i];
    };
    auto compute = [&](int bufi) {
#pragma unroll
        for (int ks2 = 0; ks2 < BK / 32; ks2++) {
            short8 af[FM], bf[FN];
#pragma unroll
            for (int i = 0; i < FM; i++)
                af[i] = *(const short8*)&As[bufi][
                    (wr * FM * 16 + i * 16 + l16) * LDAx + ks2 * 32 + quad * 8];
#pragma unroll
            for (int j = 0; j < FN; j++)
                bf[j] = *(const short8*)&Bs[bufi][
                    (wc * FN * 16 + j * 16 + l16) * LDAx + ks2 * 32 + quad * 8];
#pragma unroll
            for (int i = 0; i < FM; i++)
#pragma unroll
                for (int j = 0; j < FN; j++)
                    acc[i][j] = __builtin_amdgcn_mfma_f32_16x16x32_bf16(
                        af[i], bf[j], acc[i][j], 0, 0, 0);
        }
    };

    for (int k0 = 0; k0 < K; k0 += 2 * BK) {
        // ---- even half: buffer 0 ----
        store_lds(0, sa0, sb0);
        __syncthreads();
        if (k0 + 2 * BK < K) ldg(k0 + 2 * BK, sa0, sb0);
        compute(0);
        // ---- odd half: buffer 1 ----
        store_lds(1, sa1, sb1);
        __syncthreads();
        if (k0 + 3 * BK < K) ldg(k0 + 3 * BK, sa1, sb1);
        compute(1);
    }

    if constexpr (EPI == 1) {
        // fused conv (cols 0..1023) + mlp1 (1024..5119) + ca1 (5120..5183) +
        // pad (5184..5247, skip). All boundaries 64-aligned -> wave-uniform.
        float wmx = softw(wvec, 2);
        float w0c = softw(wvec, 0);
        float w14c = softw(wvec, 1) + softw(wvec, 4);
        int colbase = n0 + wc * FN * 16;
        int region = (colbase < 1024) ? 0 : (colbase < 5120) ? 1
                   : (colbase < 5184) ? 2 : 3;
        if (region == 3) return;   // padding columns
#pragma unroll
        for (int i = 0; i < FM; i++) {
#pragma unroll
            for (int j = 0; j < FN; j++) {
                int col = colbase + j * 16 + l16;
                float bv = (region == 0) ? bias[col]
                         : (region == 1) ? be0[col - 1024]
                                         : g0[col - 5120];   // ca1_b
#pragma unroll
                for (int r = 0; r < 4; r++) {
                    int row = m0 + wr * FM * 16 + i * 16 + quad * 4 + r;
                    float v = acc[i][j][r] + bv;
                    if (region == 0) {
                        size_t idx = (size_t)row * 1024 + col;
                        float2 xl = ((const float2*)f1)[idx];
                        b0[idx] = __float2bfloat16(
                            w0c * xl.x + w14c * xl.y + wmx * gelu_f(v));
                    } else if (region == 1) {
                        b1[(size_t)row * 4096 + (col - 1024)] =
                            __float2bfloat16(gelu_f(v));
                    } else {
                        // ca1: h1 = relu(x @ ca1_w^T + b), f32
                        f0[(size_t)row * 64 + (col - 5120)] = fmaxf(v, 0.f);
                    }
                }
            }
        }
        return;
    }

    if constexpr (EPI == 5) {
        int colbase = n0 + wc * FN * 16;           // 64-aligned => one head per wave
        int portion = colbase >> 10;               // 0=q 1=k 2=v
        int hh = (colbase >> 6) & 15;
        float bv[FN];
#pragma unroll
        for (int j = 0; j < FN; j++) bv[j] = bias[colbase + j * 16 + l16];
        if (portion == 2) {
#pragma unroll
            for (int i = 0; i < FM; i++)
#pragma unroll
                for (int j = 0; j < FN; j++)
#pragma unroll
                    for (int r = 0; r < 4; r++) {
                        int row = m0 + wr * FM * 16 + i * 16 + quad * 4 + r;
                        int bb = row >> 10, nn = row & 1023;
                        int dd = j * 16 + l16;
                        b0[((size_t)(bb * 16 + hh) * DHEAD + dd) * NSEQ + nn] =
                            __float2bfloat16(acc[i][j][r] + bv[j]);
                    }
        } else {
            const float* g  = (portion == 0) ? g0 : g1;
            const float* be = (portion == 0) ? be0 : be1;
            __hip_bfloat16* dst = (portion == 0) ? b1 : b2;
            // q gain: 1/sqrt(d)=0.125 AND log2(e) (flash/attn_map use exp2)
            float qs = (portion == 0) ? 0.125f * 1.4426950408889634f : 1.0f;
            float gv[FN], bev[FN];
#pragma unroll
            for (int j = 0; j < FN; j++) {
                gv[j] = g[j * 16 + l16] * qs;
                bev[j] = be[j * 16 + l16] * qs;
            }
#pragma unroll
            for (int i = 0; i < FM; i++)
#pragma unroll
                for (int r = 0; r < 4; r++) {
                    float s1 = 0.f, s2 = 0.f;
#pragma unroll
                    for (int j = 0; j < FN; j++) {
                        float v = acc[i][j][r] + bv[j];
                        s1 += v; s2 += v * v;
                    }
#pragma unroll
                    for (int mk = 1; mk < 16; mk <<= 1) {
                        s1 += __shfl_xor(s1, mk, 64);
                        s2 += __shfl_xor(s2, mk, 64);
                    }
                    float mean = s1 * (1.f / 64.f);
                    float var = s2 * (1.f / 64.f) - mean * mean;
                    float rs = rsqrtf(var + 1e-5f);
                    int row = m0 + wr * FM * 16 + i * 16 + quad * 4 + r;
                    int bb = row >> 10, nn = row & 1023;
                    size_t base = ((size_t)(bb * 16 + hh) * NSEQ + nn) * DHEAD;
#pragma unroll
                    for (int j = 0; j < FN; j++)
                        dst[base + j * 16 + l16] = __float2bfloat16(
                            (acc[i][j][r] + bv[j] - mean) * rs * gv[j] + bev[j]);
                }
        }
        return;
    }

    float wmx = 0.f;
    if (EPI == 3) wmx = softw(wvec, 5);

#pragma unroll
    for (int i = 0; i < FM; i++) {
#pragma unroll
        for (int j = 0; j < FN; j++) {
            int col = n0 + wc * FN * 16 + j * 16 + l16;
            float bv = bias[col];
#pragma unroll
            for (int r = 0; r < 4; r++) {
                int row = m0 + wr * FM * 16 + i * 16 + quad * 4 + r;
                float v = acc[i][j][r] + bv;
                size_t idx = (size_t)row * N + col;
                if (EPI == 3) {
                    // final mix: xmixb += w5 * v (bf16 rmw)
                    float tv = __bfloat162float(b0[idx]) + wmx * v;
                    b0[idx] = __float2bfloat16(tv);
                } else if (EPI == 4) {
                    f0[idx] = v + __bfloat162float(b1[idx]);  // proj + residual
                }
            }
        }
    }
}

// ---------- ca2: xmixb += w3 * sigmoid(h1 @ ca2_w^T + b) * x  (bf16 rmw) ----------
__global__ __launch_bounds__(256) void ca2_kernel(
    const float* __restrict__ h1, const float* __restrict__ w,
    const float* __restrict__ bias, const __hip_bfloat16* __restrict__ xb,
    __hip_bfloat16* __restrict__ xmixb, const float* __restrict__ wvec)
{
    __shared__ float Wt[256 * 65];
    __shared__ float hs[16 * 64];
    int t = threadIdx.x;
    int m0 = blockIdx.x * 16, n0 = blockIdx.y * 256;
#pragma unroll
    for (int i = 0; i < 64; i++) {
        int e = t + i * 256; int r = e >> 6, c = e & 63;
        Wt[r * 65 + c] = w[(size_t)(n0 + r) * 64 + c];
    }
#pragma unroll
    for (int i = 0; i < 4; i++) {
        int e = t + i * 256; int r = e >> 6, c = e & 63;
        hs[r * 64 + c] = h1[(size_t)(m0 + r) * 64 + c];
    }
    __syncthreads();
    int n = n0 + t;
    float bv = bias[n];
    float acc[16];
#pragma unroll
    for (int mi = 0; mi < 16; mi++) acc[mi] = bv;
    for (int k = 0; k < 64; k++) {
        float wv = Wt[t * 65 + k];
#pragma unroll
        for (int mi = 0; mi < 16; mi++) acc[mi] += hs[mi * 64 + k] * wv;
    }
    float w3 = softw(wvec, 3);
#pragma unroll
    for (int mi = 0; mi < 16; mi++) {
        size_t idx = (size_t)(m0 + mi) * 1024 + n;
        float sg = 1.f / (1.f + __expf(-acc[mi]));
        float cur = __bfloat162float(xmixb[idx]);
        xmixb[idx] = __float2bfloat16(cur + w3 * sg * __bfloat162float(xb[idx]));
    }
}

// ---------- MFMA flash attention ----------
// grid (64 bh, 8 i-tiles), block 256 (4 waves). Wave owns 32 q-rows.
// XCD swizzle (T1): XCD k serves heads 8k..8k+7 -> K/V L2-resident per XCD.
// BOUNDED softmax (q,k LayerNormed => |s| <= 8*log2e): p = 2^s directly,
// no running max (exact; q carries 0.125*log2e from qkv epilogue).
// ROW-SUM VIA MFMA: synthetic ones-fragment (l16==0 lanes = bf16(1.0)) as a
// 5th PV B-tile -> o[ri][4] accumulates sum_j p in the l16==0 lanes; replaces
// the per-j-tile shfl_xor reduction (~100 VALU cyc) with 4 MFMA + 8 final shfl.
#define PSTR 72   // bf16 stride: 144 B, 16B-aligned, 2-way banks
__global__ __launch_bounds__(256) void flash_mfma(
    const __hip_bfloat16* __restrict__ qb, const __hip_bfloat16* __restrict__ kb,
    const __hip_bfloat16* __restrict__ vt, __hip_bfloat16* __restrict__ ao)
{
    __shared__ __hip_bfloat16 Plds[4][32 * PSTR];
    int l = blockIdx.y * 64 + blockIdx.x;      // hw linear id (x fastest)
    int swz = (l & 7) * 64 + (l >> 3);         // bijection on [0,512)
    int bh = swz >> 3;
    int i0 = (swz & 7) * 128;
    int b = bh >> 4, h = bh & 15;
    int t = threadIdx.x, wave = t >> 6, lane = t & 63;
    int l16 = lane & 15, quad = lane >> 4;
    const __hip_bfloat16* qbase = qb + (size_t)bh * NSEQ * DHEAD;
    const __hip_bfloat16* kbase = kb + (size_t)bh * NSEQ * DHEAD;
    const __hip_bfloat16* vbase = vt + (size_t)bh * DHEAD * NSEQ;
    __hip_bfloat16* pw = Plds[wave];
    int qrow0 = i0 + wave * 32;

    // Q fragments, held for the whole kernel (pre-scaled in qkv epi)
    short8 aq[2][2];
#pragma unroll
    for (int ri = 0; ri < 2; ri++)
#pragma unroll
        for (int ks = 0; ks < 2; ks++)
            aq[ri][ks] = *(const short8*)(qbase +
                (size_t)(qrow0 + ri * 16 + l16) * DHEAD + ks * 32 + quad * 8);

    // ones-fragment: B row 64 == 1.0 (lanes l16==0), rows 65..79 == 0
    short8 bones;
    {
        short fill = (l16 == 0) ? (short)0x3F80 : (short)0;
#pragma unroll
        for (int z = 0; z < 8; z++) bones[z] = fill;
    }

    f32x4 zero = {0.f, 0.f, 0.f, 0.f};
    f32x4 o[2][5];                 // [..][4] = row-sum accumulator
#pragma unroll
    for (int ri = 0; ri < 2; ri++)
#pragma unroll
        for (int nt = 0; nt < 5; nt++) o[ri][nt] = zero;

    for (int j0 = 0; j0 < NSEQ; j0 += 64) {
        // K fragments: B[n=key][k=d]
        short8 bk[4][2];
#pragma unroll
        for (int jt = 0; jt < 4; jt++)
#pragma unroll
            for (int ks = 0; ks < 2; ks++)
                bk[jt][ks] = *(const short8*)(kbase +
                    (size_t)(j0 + jt * 16 + l16) * DHEAD + ks * 32 + quad * 8);
        // V^T fragments: B[n=d][k=key]
        short8 bv[4][2];
#pragma unroll
        for (int nt = 0; nt < 4; nt++)
#pragma unroll
            for (int ks = 0; ks < 2; ks++)
                bv[nt][ks] = *(const short8*)(vbase +
                    (size_t)(nt * 16 + l16) * NSEQ + j0 + ks * 32 + quad * 8);

#pragma unroll
        for (int ri = 0; ri < 2; ri++) {
            f32x4 s[4];
#pragma unroll
            for (int jt = 0; jt < 4; jt++) s[jt] = zero;
#pragma unroll
            for (int jt = 0; jt < 4; jt++)
#pragma unroll
                for (int ks = 0; ks < 2; ks++)
                    s[jt] = __builtin_amdgcn_mfma_f32_16x16x32_bf16(
                        aq[ri][ks], bk[jt][ks], s[jt], 0, 0, 0);
            // bounded softmax: p = 2^s (s <= ~11.7); row = quad*4+rr
#pragma unroll
            for (int rr = 0; rr < 4; rr++)
#pragma unroll
                for (int jt = 0; jt < 4; jt++)
                    pw[(ri * 16 + quad * 4 + rr) * PSTR + jt * 16 + l16] =
                        __float2bfloat16(exp2f(s[jt][rr]));
        }
        // PV: A = P from wave-private LDS (compiler inserts lgkmcnt wait);
        // nt=4 uses the ones-fragment -> accumulates the row-sum.
#pragma unroll
        for (int ri = 0; ri < 2; ri++) {
            short8 ap[2];
#pragma unroll
            for (int ks = 0; ks < 2; ks++)
                ap[ks] = *(const short8*)&pw[(ri * 16 + l16) * PSTR + ks * 32 + quad * 8];
#pragma unroll
            for (int nt = 0; nt < 5; nt++)
#pragma unroll
                for (int ks = 0; ks < 2; ks++)
                    o[ri][nt] = __builtin_amdgcn_mfma_f32_16x16x32_bf16(
                        ap[ks], (nt == 4) ? bones : bv[nt][ks], o[ri][nt], 0, 0, 0);
        }
    }

#pragma unroll
    for (int ri = 0; ri < 2; ri++)
#pragma unroll
        for (int rr = 0; rr < 4; rr++) {
            // row-sum lives in lane quad*16 (output col 0) of o[ri][4][rr]
            float lsum = __shfl(o[ri][4][rr], quad << 4, 64);
            float inv = 1.f / lsum;
            int row = qrow0 + ri * 16 + quad * 4 + rr;
#pragma unroll
            for (int nt = 0; nt < 4; nt++)
                ao[((size_t)b * NSEQ + row) * CDIM + h * 64 + nt * 16 + l16] =
                    __float2bfloat16(o[ri][nt][rr] * inv);
        }
}

// ---------- attn_map: mean over heads of attn[:,0,1:] ----------
__global__ __launch_bounds__(256) void attn_map_acc(
    const __hip_bfloat16* __restrict__ qf, const __hip_bfloat16* __restrict__ kf,
    float* __restrict__ am)
{
    __shared__ float q0[64];
    __shared__ float red[256];
    int bh = blockIdx.x, t = threadIdx.x;
    const __hip_bfloat16* qr = qf + (size_t)bh * NSEQ * DHEAD;   // row 0
    const __hip_bfloat16* kb = kf + (size_t)bh * NSEQ * DHEAD;
    if (t < 64) q0[t] = __bfloat162float(qr[t]);   // q pre-scaled (0.125*log2e)
    __syncthreads();
    float s[4];
    float mx = -1e30f;
#pragma unroll
    for (int ji = 0; ji < 4; ji++) {
        int j = ji * 256 + t;
        float a = 0.f;
        for (int k = 0; k < 64; k++) a += q0[k] * __bfloat162float(kb[(size_t)j * 64 + k]);
        s[ji] = a;
        mx = fmaxf(mx, a);
    }
    red[t] = mx; __syncthreads();
    for (int st = 128; st > 0; st >>= 1) {
        if (t < st) red[t] = fmaxf(red[t], red[t + st]);
        __syncthreads();
    }
    float M = red[0]; __syncthreads();
    float sum = 0.f;
#pragma unroll
    for (int ji = 0; ji < 4; ji++) { s[ji] = exp2f(s[ji] - M); sum += s[ji]; }
    red[t] = sum; __syncthreads();
    for (int st = 128; st > 0; st >>= 1) {
        if (t < st) red[t] += red[t + st];
        __syncthreads();
    }
    float inv = 1.f / red[0];
    int b = bh >> 4;
#pragma unroll
    for (int ji = 0; ji < 4; ji++) {
        int j = ji * 256 + t;
        if (j > 0) atomicAdd(&am[b * 1024 + j], s[ji] * inv * (1.f / 16.f));
    }
}

__global__ __launch_bounds__(256) void attn_map_out(
    const float* __restrict__ am, float* __restrict__ out1)
{
    int i = blockIdx.x * 256 + threadIdx.x;
    if (i < 4 * 1023) {
        int b = i / 1023;
        int j = i - b * 1023 + 1;
        out1[i] = am[b * 1024 + j];
    }
}

// ---------- launch ----------
extern "C" void kernel_launch(void* const* d_in, const int* in_sizes, int n_in,
                              void* d_out, int out_size, void* d_ws, size_t ws_size,
                              hipStream_t stream)
{
    const float* x_list = (const float*)d_in[0];
    const float* wvec   = (const float*)d_in[1];
    const float* qkv_w  = (const float*)d_in[2];
    const float* qkv_b  = (const float*)d_in[3];
    const float* proj_w = (const float*)d_in[4];
    const float* proj_b = (const float*)d_in[5];
    const float* nq_g   = (const float*)d_in[6];
    const float* nq_b   = (const float*)d_in[7];
    const float* nk_g   = (const float*)d_in[8];
    const float* nk_b   = (const float*)d_in[9];
    const float* conv_w = (const float*)d_in[10];
    const float* conv_b = (const float*)d_in[11];
    const float* ca1_w  = (const float*)d_in[12];
    const float* ca1_b  = (const float*)d_in[13];
    const float* ca2_w  = (const float*)d_in[14];
    const float* ca2_b  = (const float*)d_in[15];
    const float* mlp1_w = (const float*)d_in[16];
    const float* mlp1_b = (const float*)d_in[17];
    const float* mlp2_w = (const float*)d_in[18];
    const float* mlp2_b = (const float*)d_in[19];

    float* out0 = (float*)d_out;
    float* out1 = out0 + (size_t)4 * 1024 * 1024;

    char* ws = (char*)d_ws;
    size_t off = 0;
    auto alloc = [&](size_t bytes) -> char* {
        char* p = ws + off;
        off += (bytes + 255) & ~(size_t)255;
        return p;
    };
    __hip_bfloat16* xb     = (__hip_bfloat16*)alloc((size_t)MROWS * CDIM * 2);
    __hip_bfloat16* xmixb  = (__hip_bfloat16*)alloc((size_t)MROWS * CDIM * 2);
    float*          h1     = (float*)alloc((size_t)MROWS * 64 * 4);
    __hip_bfloat16* hb     = (__hip_bfloat16*)alloc((size_t)MROWS * 4096 * 2);
    __hip_bfloat16* qbb    = (__hip_bfloat16*)alloc((size_t)MROWS * CDIM * 2);
    __hip_bfloat16* kbb    = (__hip_bfloat16*)alloc((size_t)MROWS * CDIM * 2);
    __hip_bfloat16* vtb    = (__hip_bfloat16*)alloc((size_t)MROWS * CDIM * 2);
    __hip_bfloat16* aob    = (__hip_bfloat16*)alloc((size_t)MROWS * CDIM * 2);
    float*          amacc  = (float*)alloc(4096 * 4);
    __hip_bfloat16* wcat   = (__hip_bfloat16*)alloc((size_t)5248 * 1024 * 2);  // conv|mlp1|ca1|pad
    __hip_bfloat16* qkvwb  = (__hip_bfloat16*)alloc((size_t)3145728 * 2);
    __hip_bfloat16* projwb = (__hip_bfloat16*)alloc((size_t)1048576 * 2);
    __hip_bfloat16* mlp2wb = (__hip_bfloat16*)alloc((size_t)4194304 * 2);

    // fused prologue: all weight converts + x -> bf16 (13440 + 8192 blocks)
    prep_all<<<21632, 256, 0, stream>>>(conv_w, mlp1_w, qkv_w, proj_w, mlp2_w,
                                        ca1_w, wcat, qkvwb, projwb, mlp2wb,
                                        x_list, xb, amacc);

    // fused conv+mlp1+ca1: 1D grid 1312 (SWZ=2: ca1 column prepended,
    // main blocks keep the 40-wide column->XCD pinning)
    gemm_bf16<1, 4, 4, 2, 32><<<1312, 256, 0, stream>>>(
        xb, wcat, conv_b, h1, x_list, xmixb, hb, nullptr,
        ca1_b, mlp1_b, nullptr, nullptr, wvec, MROWS, 5248, 1024);

    // channel attention part 2: xmixb += w3*sig(h1 @ ca2_w^T + b)*x (bf16 rmw)
    ca2_kernel<<<dim3(256, 4), 256, 0, stream>>>(h1, ca2_w, ca2_b, xb, xmixb, wvec);

    // mlp2: xmixb += w5*(hb @ mlp2_w^T + b)  [64x128 tile, 512 blocks, BK=64:
    // halves barrier-drain count over K=4096; LDS 55.3 KB keeps 2 blocks/CU]
    gemm_bf16<3, 2, 4, 1, 64><<<dim3(8, 64), 256, 0, stream>>>(
        hb, mlp2wb, mlp2_b, nullptr, nullptr, xmixb, nullptr, nullptr,
        nullptr, nullptr, nullptr, nullptr, wvec, MROWS, 1024, 4096);

    // qkv with fused per-head LN: q->qbb (x 0.125*log2e), k->kbb; v->V^T
    gemm_bf16<5, 4, 4, 1, 32><<<dim3(24, 32), 256, 0, stream>>>(
        xmixb, qkvwb, qkv_b, nullptr, nullptr, vtb, qbb, kbb,
        nq_g, nq_b, nk_g, nk_b, wvec, MROWS, 3072, 1024);

    // attention (MFMA, bh-major XCD swizzle, bounded exp2 softmax, MFMA row-sum)
    flash_mfma<<<dim3(64, 8), 256, 0, stream>>>(qbb, kbb, vtb, aob);

    // attn_map
    attn_map_acc<<<64, 256, 0, stream>>>(qbb, kbb, amacc);
    attn_map_out<<<16, 256, 0, stream>>>(amacc, out1);

    // projection + residual  [64x128 tile, 512 blocks]
    gemm_bf16<4, 2, 4, 1, 32><<<dim3(8, 64), 256, 0, stream>>>(
        aob, projwb, proj_b, out0, nullptr, nullptr, xmixb, nullptr,
        nullptr, nullptr, nullptr, nullptr, wvec, MROWS, 1024, 1024);
}